// Round 5
// baseline (149.589 us; speedup 1.0000x reference)
//
#include <hip/hip_runtime.h>
#include <hip/hip_bf16.h>

#define VOCAB 512
#define W 20
#define R 4   // rows per block, one per wave

typedef float f4 __attribute__((ext_vector_type(4)));

// Zeros-first structure: the 8 KB of (mostly-zero) output per block is stored
// immediately with NO input dependency (pure fill, runs at HBM fill rate).
// After a block barrier, each wave combines its row's 20 (char, weight) pairs
// in-register (duplicate chars summed via lane broadcast) and scatter-stores
// the <=20 nonzero dwords into the L2-resident lines. No LDS, no atomics.
// Requires rows % R == 0 (holds: 65536 % 4 == 0).
__global__ __launch_bounds__(256) void fofe_kernel(
    const int*   __restrict__ sents,    // [rows * W]
    const int*   __restrict__ lengths,  // [B]
    const float* __restrict__ alpha_p,  // [1]
    float*       __restrict__ out,      // [rows * VOCAB + B]
    int rows, int B)
{
    const int tid  = threadIdx.x;
    const int wv   = tid >> 6;          // 0..3: row within block
    const int lane = tid & 63;
    const int row  = blockIdx.x * R + wv;
    const bool act = (lane < W);        // lanes holding a (char, weight) pair

    // --- issue the long-latency char load FIRST; it overlaps phase 1 ---
    int   c = -1;
    float w = 0.f;
    if (act) {
        c = sents[(size_t)row * W + lane];
        const float alpha = alpha_p[0];
        // alpha^(W-1-lane); lane W-1 pinned to exactly 1 (also dodges -inf*0 at alpha==0)
        w = (lane == W - 1) ? 1.0f : exp2f(log2f(alpha) * (float)(W - 1 - lane));
    }

    // --- phase 1: zero-store the block's contiguous 8 KB output region.
    //     Pure dependency-free fill: 2 x global_store_dwordx4 per thread. ---
    {
        f4* o4 = (f4*)(out + (size_t)blockIdx.x * R * VOCAB);
        const f4 z = (f4){0.f, 0.f, 0.f, 0.f};
        o4[tid]       = z;
        o4[tid + 256] = z;
    }

    // --- output 1: lengths pass-through as floats (no ordering hazard) ---
    if (blockIdx.x == 0 && tid < B) {
        out[(size_t)rows * VOCAB + tid] = (float)lengths[tid];
    }

    // __syncthreads drains vmcnt before s_barrier -> phase-1 stores are
    // globally ordered before any phase-2 store to the same addresses.
    __syncthreads();

    // --- phase 2: in-register duplicate combine + sparse scatter ---
    // tot_k = sum_j w_j * [c_j == c_k]; only the first lane holding each
    // char value writes, so scatter addresses are unique per row.
    float tot   = 0.f;
    bool  first = true;
    #pragma unroll
    for (int j = 0; j < W; ++j) {
        const int   cj = __shfl(c, j);   // source lanes 0..19 hold valid values
        const float wj = __shfl(w, j);
        if (cj == c) {
            tot += wj;
            if (j < lane) first = false;
        }
    }
    if (act && first) {
        out[(size_t)row * VOCAB + c] = tot;   // hits L2-resident line from phase 1
    }
}

extern "C" void kernel_launch(void* const* d_in, const int* in_sizes, int n_in,
                              void* d_out, int out_size, void* d_ws, size_t ws_size,
                              hipStream_t stream) {
    const int*   sents   = (const int*)d_in[0];    // [B*S*W] int32
    const int*   lengths = (const int*)d_in[1];    // [B] int32
    const float* alpha   = (const float*)d_in[2];  // [1] float32
    float*       out     = (float*)d_out;

    const int rows = in_sizes[0] / W;   // B*S = 65536
    const int B    = in_sizes[1];       // 256

    const int blocks = rows / R;        // 16384
    fofe_kernel<<<blocks, 256, 0, stream>>>(sents, lengths, alpha, out, rows, B);
}

// Round 6
// 144.453 us; speedup vs baseline: 1.0356x; 1.0356x over previous
//
#include <hip/hip_runtime.h>
#include <hip/hip_bf16.h>

#define VOCAB 512
#define W 20
#define R 8   // rows per block

typedef float f4 __attribute__((ext_vector_type(4)));

// BEST CONFIG (R4): 256-thread block builds R=8 consecutive rows in 16 KB LDS,
// then streams them out as one contiguous 16 KB burst (4 x dwordx4/thread).
// Stores issue once, at the end, with no trailing barrier — block exit overlaps
// store completion across the 8 resident blocks/CU. Bench window is dominated
// by ~110 us of harness poison fills (512 MiB d_ws + 134 MB d_out); kernel
// itself sits at ~25-35 us vs a 21 us HBM write floor.
__global__ __launch_bounds__(256) void fofe_kernel(
    const int*   __restrict__ sents,    // [rows * W]
    const int*   __restrict__ lengths,  // [B]
    const float* __restrict__ alpha_p,  // [1]
    float*       __restrict__ out,      // [rows * VOCAB + B]
    int rows, int B)
{
    __shared__ float lds[R * VOCAB];    // 16 KB

    const int tid  = threadIdx.x;
    const int row0 = blockIdx.x * R;

    // --- issue the char loads FIRST (long-latency), overlap with LDS zeroing ---
    float w = 0.f;
    int   c = 0;
    int   r = 0;
    if (tid < R * W) {
        r = tid / W;                       // row within block
        const int k = tid - r * W;         // char position
        c = sents[(size_t)(row0 + r) * W + k];   // coalesced 640 B block load
        const float alpha = alpha_p[0];
        w = exp2f(log2f(alpha) * (float)(W - 1 - k));
        if (k == W - 1) w = 1.0f;          // alpha^0 == 1; dodges -inf*0 at alpha==0
    }

    // --- zero 16 KB LDS: 4 x f4 per thread ---
    f4* l4 = (f4*)lds;
    #pragma unroll
    for (int i = 0; i < 4; ++i)
        l4[tid + 256 * i] = (f4){0.f, 0.f, 0.f, 0.f};

    __syncthreads();

    // --- scatter decay weights (ds_add_f32 handles duplicate chars) ---
    if (tid < R * W)
        atomicAdd(&lds[r * VOCAB + c], w);

    __syncthreads();

    // --- contiguous 16 KB streaming write-out: 4 x global_store_dwordx4 ---
    f4* o4 = (f4*)(out + (size_t)row0 * VOCAB);
    #pragma unroll
    for (int i = 0; i < 4; ++i)
        __builtin_nontemporal_store(l4[tid + 256 * i], &o4[tid + 256 * i]);

    // --- output 1: lengths pass-through as float values at the tail ---
    if (blockIdx.x == 0 && tid < B) {
        out[(size_t)rows * VOCAB + tid] = (float)lengths[tid];
    }
}

extern "C" void kernel_launch(void* const* d_in, const int* in_sizes, int n_in,
                              void* d_out, int out_size, void* d_ws, size_t ws_size,
                              hipStream_t stream) {
    const int*   sents   = (const int*)d_in[0];    // [B*S*W] int32
    const int*   lengths = (const int*)d_in[1];    // [B] int32
    const float* alpha   = (const float*)d_in[2];  // [1] float32
    float*       out     = (float*)d_out;

    const int rows = in_sizes[0] / W;   // B*S = 65536
    const int B    = in_sizes[1];       // 256

    const int blocks = (rows + R - 1) / R;   // 8192
    fofe_kernel<<<blocks, 256, 0, stream>>>(sents, lengths, alpha, out, rows, B);
}